// Round 21
// baseline (103.939 us; speedup 1.0000x reference)
//
#include <hip/hip_runtime.h>
#include <hip/hip_bf16.h>
#include <math.h>
#include <stdint.h>

#define N_NODES 100000
#define N_EDGES 1600000
#define IN_DIM 256
#define OUT_DIM 64

#define CWIN  64                          // nodes per window
#define NCB   1563                        // ceil(100000/64)
#define NPART 256                         // 256 * 6250 = 1.6M exact
#define EPP   (N_EDGES / NPART)           // 6250
#define SCAN_N (NCB * NPART)              // 400128
#define SCAN_BLK ((SCAN_N + 4095) / 4096) // 98
#define MAXE  1536                        // window edge cap (mean 1024, ~16 sigma)

#define GEMM_BLKS ((N_NODES + 255) / 256) // 391 blocks x 256 nodes (16 waves)

// cur2dT[part * NCB + win] (transposed storage; logical L = win*NPART+part)
// Wh stored PERMUTED: Wh'[row][cl*4+nt] = Wh[row][nt*16+cl]

typedef __attribute__((ext_vector_type(8))) short bh8;   // 8 x bf16 frag
typedef __attribute__((ext_vector_type(4))) float f4;    // mfma accumulator

typedef __attribute__((address_space(1))) const void GV;
typedef __attribute__((address_space(3))) void LV;

// f32 -> bf16 round-to-nearest-even
static __device__ __forceinline__ unsigned short f2bf(float f) {
    unsigned u = __float_as_uint(f);
    unsigned r = (u + 0x7FFFu + ((u >> 16) & 1u)) >> 16;
    return (unsigned short)r;
}

// ---------------------------------------------------------------------------
// W prep: f32 W[64][256] -> bf16 WB in MFMA B-frag layout (2048 cells).
// ---------------------------------------------------------------------------
__global__ __launch_bounds__(64) void gat_wprep(const float* __restrict__ W,
                                                unsigned short* __restrict__ WB)
{
    const int cell = blockIdx.x * 64 + threadIdx.x;   // 0..2047
    const int cl = cell & 15;
    const int nt = (cell >> 4) & 3;
    const int k16 = cell >> 6;                        // 0..31
    const int col = nt * 16 + cl;
    const float4 lo = *(const float4*)(W + col * IN_DIM + k16 * 8);
    const float4 hi = *(const float4*)(W + col * IN_DIM + k16 * 8 + 4);
    unsigned short tmp[8];
    tmp[0] = f2bf(lo.x); tmp[1] = f2bf(lo.y);
    tmp[2] = f2bf(lo.z); tmp[3] = f2bf(lo.w);
    tmp[4] = f2bf(hi.x); tmp[5] = f2bf(hi.y);
    tmp[6] = f2bf(hi.z); tmp[7] = f2bf(hi.w);
    *(uint4*)&WB[(size_t)cell * 8] = *(uint4*)tmp;
}

// ---------------------------------------------------------------------------
// Kernel A (MFMA) v10: ASM-ISSUED full-row h prefetch.
// Per wave: 16 inline-asm global_load_dwordx4 (whole K=256 row slice, 64
// VGPRs) issued back-to-back -- asm volatile cannot be sunk by the compiler
// (R14's C++ attempt was; VGPR=52 proved it). Then W DMA, then ONE barrier
// whose vmcnt(0) drains h+W together in a single latency round. K-loop is
// pure register+LDS, zero stalls. 1024-thr blocks (16 waves share W copy).
// ---------------------------------------------------------------------------
__global__ __launch_bounds__(1024) void gat_gemm(
    const float* __restrict__ h, const unsigned short* __restrict__ WB,
    const float* __restrict__ a, unsigned short* __restrict__ WhB,
    float* __restrict__ p_src, float* __restrict__ p_dst,
    const int* __restrict__ dst, int* __restrict__ cur2dT)
{
    __shared__ __align__(16) unsigned short Wlds[64 * 256];   // 32 KB

    const int t = threadIdx.x;

    // ---- hist role ----
    if (blockIdx.x >= GEMM_BLKS) {
        const int part = blockIdx.x - GEMM_BLKS;
        int* lh = (int*)Wlds;
        for (int i = t; i < NCB; i += 1024) lh[i] = 0;
        __syncthreads();
        const int e0 = part * EPP;
        for (int e = e0 + t; e < e0 + EPP; e += 1024)
            atomicAdd(&lh[dst[e] >> 6], 1);
        __syncthreads();
        for (int i = t; i < NCB; i += 1024)
            cur2dT[part * NCB + i] = lh[i];
        return;
    }

    // ---- gemm role ----
    const int lane = t & 63;
    const int wv = t >> 6;                 // 0..15
    const int cl = lane & 15;
    const int g  = lane >> 4;
    const int node0 = blockIdx.x * 256 + wv * 16;

    int row = node0 + cl;
    row = (row < N_NODES) ? row : N_NODES - 1;
    const float* __restrict__ hp = h + (size_t)row * IN_DIM + g * 8;

    // issue ALL 16 h loads via inline asm (un-sinkable, all in flight)
    float4 lo0, lo1, lo2, lo3, lo4, lo5, lo6, lo7;
    float4 hi0, hi1, hi2, hi3, hi4, hi5, hi6, hi7;
    #define LD(dst_, off_)                                                     \
        asm volatile("global_load_dwordx4 %0, %1, off offset:" #off_           \
                     : "=&v"(dst_) : "v"(hp))
    LD(lo0, 0);    LD(hi0, 16);
    LD(lo1, 128);  LD(hi1, 144);
    LD(lo2, 256);  LD(hi2, 272);
    LD(lo3, 384);  LD(hi3, 400);
    LD(lo4, 512);  LD(hi4, 528);
    LD(lo5, 640);  LD(hi5, 656);
    LD(lo6, 768);  LD(hi6, 784);
    LD(lo7, 896);  LD(hi7, 912);
    #undef LD

    // stage W: 16 waves x 2 x 1KB DMA (linear frag-layout copy)
    {
        #pragma unroll
        for (int i = 0; i < 2; ++i) {
            const int chunk = wv * 2 + i;
            __builtin_amdgcn_global_load_lds(
                (GV*)(WB + chunk * 512 + lane * 8),
                (LV*)(((char*)Wlds) + chunk * 1024), 16, 0, 0);
        }
    }
    // one drain for h + W together (insurance per rule #18, then barrier)
    asm volatile("s_waitcnt vmcnt(0)" ::: "memory");
    __builtin_amdgcn_sched_barrier(0);
    __syncthreads();

    f4 acc[4];
    #pragma unroll
    for (int nt = 0; nt < 4; ++nt) acc[nt] = (f4){0.f, 0.f, 0.f, 0.f};

    const float4 lov[8] = {lo0, lo1, lo2, lo3, lo4, lo5, lo6, lo7};
    const float4 hiv[8] = {hi0, hi1, hi2, hi3, hi4, hi5, hi6, hi7};

    #pragma unroll
    for (int j = 0; j < 8; ++j) {
        bh8 af;
        af[0] = (short)f2bf(lov[j].x); af[1] = (short)f2bf(lov[j].y);
        af[2] = (short)f2bf(lov[j].z); af[3] = (short)f2bf(lov[j].w);
        af[4] = (short)f2bf(hiv[j].x); af[5] = (short)f2bf(hiv[j].y);
        af[6] = (short)f2bf(hiv[j].z); af[7] = (short)f2bf(hiv[j].w);

        #pragma unroll
        for (int nt = 0; nt < 4; ++nt) {
            const bh8 bf = *(const bh8*)&Wlds[(((j * 4 + g) * 64) + nt * 16 + cl) * 8];
            acc[nt] = __builtin_amdgcn_mfma_f32_16x16x32_bf16(af, bf, acc[nt], 0, 0, 0);
        }
    }

    float aS[4], aD[4];
    #pragma unroll
    for (int nt = 0; nt < 4; ++nt) {
        aS[nt] = a[nt * 16 + cl];
        aD[nt] = a[OUT_DIM + nt * 16 + cl];
    }

    #pragma unroll
    for (int r = 0; r < 4; ++r) {
        const int orow = node0 + g * 4 + r;
        float ps = 0.f, pd = 0.f;
        #pragma unroll
        for (int nt = 0; nt < 4; ++nt) {
            ps = fmaf(acc[nt][r], aS[nt], ps);
            pd = fmaf(acc[nt][r], aD[nt], pd);
        }
        #pragma unroll
        for (int o = 8; o > 0; o >>= 1) {
            ps += __shfl_xor(ps, o);
            pd += __shfl_xor(pd, o);
        }
        if (orow < N_NODES) {
            const unsigned lo2b = (unsigned)f2bf(acc[0][r]) |
                                  ((unsigned)f2bf(acc[1][r]) << 16);
            const unsigned hi2b = (unsigned)f2bf(acc[2][r]) |
                                  ((unsigned)f2bf(acc[3][r]) << 16);
            *(uint2*)&WhB[(size_t)orow * OUT_DIM + cl * 4] = make_uint2(lo2b, hi2b);
            if (cl == 0) { p_src[orow] = ps; p_dst[orow] = pd; }
        }
    }
}

// ---------------------------------------------------------------------------
// scan1: exclusive scan in LOGICAL order over transposed storage; publishes
// RAW per-block totals to bsum (consumers do the 98-prefix inline).
// ---------------------------------------------------------------------------
__global__ __launch_bounds__(1024) void gat_scan1(int* __restrict__ data,
                                                  int* __restrict__ bsum)
{
    __shared__ int ts[1024];
    const int Lbase = blockIdx.x * 4096 + threadIdx.x * 4;
    int v[4], S[4];
    #pragma unroll
    for (int j = 0; j < 4; ++j) {
        const int L = Lbase + j;
        S[j] = (L & 255) * NCB + (L >> 8);
        v[j] = (L < SCAN_N) ? data[S[j]] : 0;
    }
    const int tsum = v[0] + v[1] + v[2] + v[3];
    ts[threadIdx.x] = tsum;
    __syncthreads();
    int val = tsum;
    for (int s = 1; s < 1024; s <<= 1) {
        const int add = (threadIdx.x >= s) ? ts[threadIdx.x - s] : 0;
        __syncthreads();
        val += add;
        ts[threadIdx.x] = val;
        __syncthreads();
    }
    int run = val - tsum;
    #pragma unroll
    for (int j = 0; j < 4; ++j) {
        const int L = Lbase + j;
        if (L < SCAN_N) data[S[j]] = run;
        run += v[j];
    }
    if (threadIdx.x == 1023) bsum[blockIdx.x] = val;   // raw total
}

// ---------------------------------------------------------------------------
// Inline 98-element exclusive prefix of bsum into pbs[] (LDS), 2-wave scan.
// ---------------------------------------------------------------------------
#define INLINE_BSUM_PREFIX(pbs, w0s)                                          \
{                                                                             \
    if (threadIdx.x < 128) {                                                  \
        const int v_ = (threadIdx.x < SCAN_BLK) ? bsum[threadIdx.x] : 0;      \
        int val_ = v_;                                                        \
        _Pragma("unroll")                                                     \
        for (int s_ = 1; s_ < 64; s_ <<= 1) {                                 \
            const int n_ = __shfl_up(val_, s_);                               \
            if ((threadIdx.x & 63) >= s_) val_ += n_;                         \
        }                                                                     \
        if (threadIdx.x == 63) w0s = val_;                                    \
        pbs[threadIdx.x] = val_ - v_;                                         \
    }                                                                         \
    __syncthreads();                                                          \
    if (threadIdx.x >= 64 && threadIdx.x < 128) pbs[threadIdx.x] += w0s;      \
    __syncthreads();                                                          \
}

// ---------------------------------------------------------------------------
// Coarse scatter: lcur from transposed row + inline bsum prefix.
// Entry: src | (dst&63)<<17.
// ---------------------------------------------------------------------------
__global__ __launch_bounds__(256) void gat_scatter_coarse(
    const int* __restrict__ src, const int* __restrict__ dst,
    const int* __restrict__ cur2dT, const int* __restrict__ bsum,
    int* __restrict__ ebufA)
{
    __shared__ int lcur[NCB];
    __shared__ int pbs[128];
    __shared__ int w0s;

    INLINE_BSUM_PREFIX(pbs, w0s)

    for (int i = threadIdx.x; i < NCB; i += 256) {
        const int L = i * NPART + blockIdx.x;
        lcur[i] = cur2dT[blockIdx.x * NCB + i] + pbs[L >> 12];
    }
    __syncthreads();
    const int e0 = blockIdx.x * EPP;
    for (int e = e0 + threadIdx.x; e < e0 + EPP; e += 256) {
        const int se = src[e], de = dst[e];
        const int pos = atomicAdd(&lcur[de >> 6], 1);
        ebufA[pos] = se | ((de & (CWIN - 1)) << 17);
    }
}

// ---------------------------------------------------------------------------
// Fused node-sort + aggregation; out-store remapped for permuted Wh.
// ---------------------------------------------------------------------------
__global__ __launch_bounds__(256) void gat_agg_fused(
    const int* __restrict__ ebufA, const int* __restrict__ cur2dT,
    const int* __restrict__ bsum,
    const float* __restrict__ p_src, const float* __restrict__ p_dst,
    const unsigned short* __restrict__ Wh, float* __restrict__ out)
{
    __shared__ int2 ledge[MAXE];          // 12 KB: {sv, ex_bits} binned
    __shared__ int lhist[CWIN], lbase[CWIN];
    __shared__ float pdl[CWIN];
    __shared__ int pbs[128];
    __shared__ int w0s;

    const int t = threadIdx.x;
    const int cb = blockIdx.x;

    INLINE_BSUM_PREFIX(pbs, w0s)

    const int a0 = cur2dT[cb] + pbs[cb >> 4];
    int a1 = N_EDGES;
    if (cb < NCB - 1) a1 = cur2dT[cb + 1] + pbs[(cb + 1) >> 4];
    const int cnt = min(a1 - a0, MAXE);
    const int wbase = cb * CWIN;

    if (t < CWIN) {
        lhist[t] = 0;
        const int node = wbase + t;
        pdl[t] = (node < N_NODES) ? p_dst[node] : 0.f;
    }
    __syncthreads();

    int   ev[6], rk[6];
    float ps[6];
    #pragma unroll
    for (int j = 0; j < 6; ++j) {
        const int i = t + j * 256;
        ev[j] = 0; rk[j] = 0; ps[j] = 0.f;
        if (i < cnt) {
            const int e = ebufA[a0 + i];
            ev[j] = e;
            ps[j] = p_src[e & 0x1FFFF];
            rk[j] = atomicAdd(&lhist[(e >> 17) & (CWIN - 1)], 1);
        }
    }
    __syncthreads();

    if (t < 64) {
        const int own = lhist[t];
        int val = own;
        #pragma unroll
        for (int s = 1; s < 64; s <<= 1) {
            const int n = __shfl_up(val, s);
            if (t >= s) val += n;
        }
        lbase[t] = val - own;
    }
    __syncthreads();

    #pragma unroll
    for (int j = 0; j < 6; ++j) {
        const int i = t + j * 256;
        if (i < cnt) {
            const int e = ev[j];
            const int ln = (e >> 17) & (CWIN - 1);
            const float ex = __expf(fmaxf(ps[j] + pdl[ln], 0.f));
            ledge[lbase[ln] + rk[j]] = make_int2(e & 0x1FFFF, __float_as_int(ex));
        }
    }
    __syncthreads();

    const int lane = t & 63;
    const int wv = t >> 6;
    const int grp = lane >> 4;
    const int ci = lane & 15;
    const int c4 = ci * 4;

    #pragma unroll
    for (int rr = 0; rr < 4; ++rr) {
        const int ln = wv * 16 + rr * 4 + grp;
        const int node = wbase + ln;
        const int sb = lbase[ln];
        const int d  = (node < N_NODES) ? lhist[ln] : 0;

        float ssum = 0.f;
        float a0f = 0.f, a1f = 0.f, a2f = 0.f, a3f = 0.f;

        #pragma unroll 4
        for (int k = 0; k < d; ++k) {
            const int2 ed = ledge[sb + k];
            const float ex = __int_as_float(ed.y);
            const uint2 wr = *(const uint2*)(Wh + (size_t)ed.x * OUT_DIM + c4);
            ssum += ex;
            a0f = fmaf(ex, __uint_as_float(wr.x << 16), a0f);
            a1f = fmaf(ex, __uint_as_float(wr.x & 0xFFFF0000u), a1f);
            a2f = fmaf(ex, __uint_as_float(wr.y << 16), a2f);
            a3f = fmaf(ex, __uint_as_float(wr.y & 0xFFFF0000u), a3f);
        }

        if (node < N_NODES) {
            const float inv = (d > 0) ? 1.f / ssum : 0.f;
            float* ob = out + (size_t)node * OUT_DIM;
            ob[ci]      = a0f * inv;
            ob[16 + ci] = a1f * inv;
            ob[32 + ci] = a2f * inv;
            ob[48 + ci] = a3f * inv;
        }
    }
}

// ---------------------------------------------------------------------------
extern "C" void kernel_launch(void* const* d_in, const int* in_sizes, int n_in,
                              void* d_out, int out_size, void* d_ws, size_t ws_size,
                              hipStream_t stream)
{
    const float* h  = (const float*)d_in[0];
    const int* src  = (const int*)d_in[1];
    const int* dst  = (const int*)d_in[2];
    const float* W  = (const float*)d_in[3];
    const float* a  = (const float*)d_in[4];
    float* out = (float*)d_out;

    // workspace layout (bytes); every buffer write-before-read
    char* ws = (char*)d_ws;
    unsigned short* WhB = (unsigned short*)(ws);      // 12,800,000 (bf16, permuted)
    float* p_src   = (float*)(ws + 12800000);         //    400,000
    float* p_dst   = (float*)(ws + 13200000);         //    400,000
    int*   cur2dT  = (int*)  (ws + 13600000);         //  1,600,512 (256*1563)
    int*   bsum    = (int*)  (ws + 15200512);         //        392
    int*   ebufA   = (int*)  (ws + 15200904);         //  6,400,000
    unsigned short* WB = (unsigned short*)(ws + 21601024); // 32,768 B, 256-aligned

    gat_wprep<<<32, 64, 0, stream>>>(W, WB);
    gat_gemm<<<GEMM_BLKS + NPART, 1024, 0, stream>>>(h, WB, a, WhB, p_src, p_dst,
                                                     dst, cur2dT);
    gat_scan1<<<SCAN_BLK, 1024, 0, stream>>>(cur2dT, bsum);
    gat_scatter_coarse<<<NPART, 256, 0, stream>>>(src, dst, cur2dT, bsum, ebufA);
    gat_agg_fused<<<NCB, 256, 0, stream>>>(ebufA, cur2dT, bsum, p_src, p_dst,
                                           WhB, out);
}

// Round 22
// 89.852 us; speedup vs baseline: 1.1568x; 1.1568x over previous
//
#include <hip/hip_runtime.h>
#include <hip/hip_bf16.h>
#include <math.h>
#include <stdint.h>

#define N_NODES 100000
#define N_EDGES 1600000
#define IN_DIM 256
#define OUT_DIM 64

#define CWIN  64                          // nodes per window
#define NCB   1563                        // ceil(100000/64)
#define NPART 256                         // 256 * 6250 = 1.6M exact
#define EPP   (N_EDGES / NPART)           // 6250
#define SCAN_N (NCB * NPART)              // 400128
#define SCAN_BLK ((SCAN_N + 4095) / 4096) // 98
#define MAXE  1536                        // window edge cap (mean 1024, ~16 sigma)

#define GEMM_BLKS ((N_NODES + 255) / 256) // 391 blocks x 256 nodes (16 waves)

// cur2dT[part * NCB + win] (transposed storage; logical L = win*NPART+part)
// Wh stored PERMUTED: Wh'[row][cl*4+nt] = Wh[row][nt*16+cl]

typedef __attribute__((ext_vector_type(8))) short bh8;   // 8 x bf16 frag
typedef __attribute__((ext_vector_type(4))) float f4;    // mfma accumulator

typedef __attribute__((address_space(1))) const void GV;
typedef __attribute__((address_space(3))) void LV;

// f32 -> bf16 round-to-nearest-even
static __device__ __forceinline__ unsigned short f2bf(float f) {
    unsigned u = __float_as_uint(f);
    unsigned r = (u + 0x7FFFu + ((u >> 16) & 1u)) >> 16;
    return (unsigned short)r;
}

// ---------------------------------------------------------------------------
// Launch A: hist (blocks 0..NPART-1) ∥ wprep (blocks NPART..NPART+1).
// Both depend only on inputs; they share one launch to cut overhead.
// ---------------------------------------------------------------------------
__global__ __launch_bounds__(1024) void gat_hist_wprep(
    const int* __restrict__ dst, int* __restrict__ cur2dT,
    const float* __restrict__ W, unsigned short* __restrict__ WB)
{
    const int t = threadIdx.x;

    if (blockIdx.x >= NPART) {
        // ---- wprep role: 2 blocks x 1024 threads = 2048 cells exactly ----
        const int cell = (blockIdx.x - NPART) * 1024 + t;
        const int cl = cell & 15;
        const int nt = (cell >> 4) & 3;
        const int k16 = cell >> 6;                    // 0..31
        const int col = nt * 16 + cl;
        const float4 lo = *(const float4*)(W + col * IN_DIM + k16 * 8);
        const float4 hi = *(const float4*)(W + col * IN_DIM + k16 * 8 + 4);
        unsigned short tmp[8];
        tmp[0] = f2bf(lo.x); tmp[1] = f2bf(lo.y);
        tmp[2] = f2bf(lo.z); tmp[3] = f2bf(lo.w);
        tmp[4] = f2bf(hi.x); tmp[5] = f2bf(hi.y);
        tmp[6] = f2bf(hi.z); tmp[7] = f2bf(hi.w);
        *(uint4*)&WB[(size_t)cell * 8] = *(uint4*)tmp;
        return;
    }

    // ---- hist role ----
    __shared__ int lh[NCB];
    for (int i = t; i < NCB; i += 1024) lh[i] = 0;
    __syncthreads();
    const int e0 = blockIdx.x * EPP;
    for (int e = e0 + t; e < e0 + EPP; e += 1024)
        atomicAdd(&lh[dst[e] >> 6], 1);
    __syncthreads();
    for (int i = t; i < NCB; i += 1024)
        cur2dT[blockIdx.x * NCB + i] = lh[i];
}

// ---------------------------------------------------------------------------
// Launch B: scan1 — exclusive scan in LOGICAL order over transposed storage;
// publishes RAW per-block totals (consumers do the 98-prefix inline).
// ---------------------------------------------------------------------------
__global__ __launch_bounds__(1024) void gat_scan1(int* __restrict__ data,
                                                  int* __restrict__ bsum)
{
    __shared__ int ts[1024];
    const int Lbase = blockIdx.x * 4096 + threadIdx.x * 4;
    int v[4], S[4];
    #pragma unroll
    for (int j = 0; j < 4; ++j) {
        const int L = Lbase + j;
        S[j] = (L & 255) * NCB + (L >> 8);
        v[j] = (L < SCAN_N) ? data[S[j]] : 0;
    }
    const int tsum = v[0] + v[1] + v[2] + v[3];
    ts[threadIdx.x] = tsum;
    __syncthreads();
    int val = tsum;
    for (int s = 1; s < 1024; s <<= 1) {
        const int add = (threadIdx.x >= s) ? ts[threadIdx.x - s] : 0;
        __syncthreads();
        val += add;
        ts[threadIdx.x] = val;
        __syncthreads();
    }
    int run = val - tsum;
    #pragma unroll
    for (int j = 0; j < 4; ++j) {
        const int L = Lbase + j;
        if (L < SCAN_N) data[S[j]] = run;
        run += v[j];
    }
    if (threadIdx.x == 1023) bsum[blockIdx.x] = val;   // raw total
}

// ---------------------------------------------------------------------------
// Inline 98-element exclusive prefix of bsum into pbs[] (LDS), 2-wave scan.
// ---------------------------------------------------------------------------
#define INLINE_BSUM_PREFIX(pbs, w0s)                                          \
{                                                                             \
    if (threadIdx.x < 128) {                                                  \
        const int v_ = (threadIdx.x < SCAN_BLK) ? bsum[threadIdx.x] : 0;      \
        int val_ = v_;                                                        \
        _Pragma("unroll")                                                     \
        for (int s_ = 1; s_ < 64; s_ <<= 1) {                                 \
            const int n_ = __shfl_up(val_, s_);                               \
            if ((threadIdx.x & 63) >= s_) val_ += n_;                         \
        }                                                                     \
        if (threadIdx.x == 63) w0s = val_;                                    \
        pbs[threadIdx.x] = val_ - v_;                                         \
    }                                                                         \
    __syncthreads();                                                          \
    if (threadIdx.x >= 64 && threadIdx.x < 128) pbs[threadIdx.x] += w0s;      \
    __syncthreads();                                                          \
}

// ---------------------------------------------------------------------------
// Launch C: gemm (blocks 0..GEMM_BLKS-1) ∥ scatter (blocks GEMM_BLKS..+NPART).
// The CSR scatter is independent of the gemm -> its ~8-10us of write traffic
// rides inside the gemm's latency bubbles. Scatter upgraded to 1024 thr.
// Gemm body = R20 v9 (best measured variant; 16 waves share one 32KB W).
// ---------------------------------------------------------------------------
__global__ __launch_bounds__(1024) void gat_gemm_scatter(
    const float* __restrict__ h, const unsigned short* __restrict__ WB,
    const float* __restrict__ a, unsigned short* __restrict__ WhB,
    float* __restrict__ p_src, float* __restrict__ p_dst,
    const int* __restrict__ src, const int* __restrict__ dst,
    const int* __restrict__ cur2dT, const int* __restrict__ bsum,
    int* __restrict__ ebufA)
{
    __shared__ __align__(16) unsigned short Wlds[64 * 256];   // 32 KB
    __shared__ int pbs[128];
    __shared__ int w0s;

    const int t = threadIdx.x;

    // ---- scatter role ----
    if (blockIdx.x >= GEMM_BLKS) {
        const int part = blockIdx.x - GEMM_BLKS;
        int* lcur = (int*)Wlds;                       // alias (6.3 KB used)

        INLINE_BSUM_PREFIX(pbs, w0s)

        for (int i = t; i < NCB; i += 1024) {
            const int L = i * NPART + part;
            lcur[i] = cur2dT[part * NCB + i] + pbs[L >> 12];
        }
        __syncthreads();
        const int e0 = part * EPP;
        for (int e = e0 + t; e < e0 + EPP; e += 1024) {
            const int se = src[e], de = dst[e];
            const int pos = atomicAdd(&lcur[de >> 6], 1);
            ebufA[pos] = se | ((de & (CWIN - 1)) << 17);
        }
        return;
    }

    // ---- gemm role (R20 v9 body) ----
    const int lane = t & 63;
    const int wv = t >> 6;                 // 0..15
    const int cl = lane & 15;
    const int g  = lane >> 4;
    const int node0 = blockIdx.x * 256 + wv * 16;

    {
        #pragma unroll
        for (int i = 0; i < 2; ++i) {
            const int chunk = wv * 2 + i;
            __builtin_amdgcn_global_load_lds(
                (GV*)(WB + chunk * 512 + lane * 8),
                (LV*)(((char*)Wlds) + chunk * 1024), 16, 0, 0);
        }
    }
    __syncthreads();

    int row = node0 + cl;
    row = (row < N_NODES) ? row : N_NODES - 1;
    const float* __restrict__ hp = h + (size_t)row * IN_DIM + g * 8;

    f4 acc[4];
    #pragma unroll
    for (int nt = 0; nt < 4; ++nt) acc[nt] = (f4){0.f, 0.f, 0.f, 0.f};

    #pragma unroll
    for (int j = 0; j < 8; ++j) {
        const float4 lo = *(const float4*)(hp + j * 32);
        const float4 hi = *(const float4*)(hp + j * 32 + 4);
        bh8 af;
        af[0] = (short)f2bf(lo.x); af[1] = (short)f2bf(lo.y);
        af[2] = (short)f2bf(lo.z); af[3] = (short)f2bf(lo.w);
        af[4] = (short)f2bf(hi.x); af[5] = (short)f2bf(hi.y);
        af[6] = (short)f2bf(hi.z); af[7] = (short)f2bf(hi.w);

        #pragma unroll
        for (int nt = 0; nt < 4; ++nt) {
            const bh8 bf = *(const bh8*)&Wlds[(((j * 4 + g) * 64) + nt * 16 + cl) * 8];
            acc[nt] = __builtin_amdgcn_mfma_f32_16x16x32_bf16(af, bf, acc[nt], 0, 0, 0);
        }
    }

    float aS[4], aD[4];
    #pragma unroll
    for (int nt = 0; nt < 4; ++nt) {
        aS[nt] = a[nt * 16 + cl];
        aD[nt] = a[OUT_DIM + nt * 16 + cl];
    }

    #pragma unroll
    for (int r = 0; r < 4; ++r) {
        const int orow = node0 + g * 4 + r;
        float ps = 0.f, pd = 0.f;
        #pragma unroll
        for (int nt = 0; nt < 4; ++nt) {
            ps = fmaf(acc[nt][r], aS[nt], ps);
            pd = fmaf(acc[nt][r], aD[nt], pd);
        }
        #pragma unroll
        for (int o = 8; o > 0; o >>= 1) {
            ps += __shfl_xor(ps, o);
            pd += __shfl_xor(pd, o);
        }
        if (orow < N_NODES) {
            const unsigned lo2 = (unsigned)f2bf(acc[0][r]) |
                                 ((unsigned)f2bf(acc[1][r]) << 16);
            const unsigned hi2 = (unsigned)f2bf(acc[2][r]) |
                                 ((unsigned)f2bf(acc[3][r]) << 16);
            *(uint2*)&WhB[(size_t)orow * OUT_DIM + cl * 4] = make_uint2(lo2, hi2);
            if (cl == 0) { p_src[orow] = ps; p_dst[orow] = pd; }
        }
    }
}

// ---------------------------------------------------------------------------
// Launch D: fused node-sort + aggregation (unchanged from R20).
// ---------------------------------------------------------------------------
__global__ __launch_bounds__(256) void gat_agg_fused(
    const int* __restrict__ ebufA, const int* __restrict__ cur2dT,
    const int* __restrict__ bsum,
    const float* __restrict__ p_src, const float* __restrict__ p_dst,
    const unsigned short* __restrict__ Wh, float* __restrict__ out)
{
    __shared__ int2 ledge[MAXE];          // 12 KB: {sv, ex_bits} binned
    __shared__ int lhist[CWIN], lbase[CWIN];
    __shared__ float pdl[CWIN];
    __shared__ int pbs[128];
    __shared__ int w0s;

    const int t = threadIdx.x;
    const int cb = blockIdx.x;

    INLINE_BSUM_PREFIX(pbs, w0s)

    const int a0 = cur2dT[cb] + pbs[cb >> 4];
    int a1 = N_EDGES;
    if (cb < NCB - 1) a1 = cur2dT[cb + 1] + pbs[(cb + 1) >> 4];
    const int cnt = min(a1 - a0, MAXE);
    const int wbase = cb * CWIN;

    if (t < CWIN) {
        lhist[t] = 0;
        const int node = wbase + t;
        pdl[t] = (node < N_NODES) ? p_dst[node] : 0.f;
    }
    __syncthreads();

    int   ev[6], rk[6];
    float ps[6];
    #pragma unroll
    for (int j = 0; j < 6; ++j) {
        const int i = t + j * 256;
        ev[j] = 0; rk[j] = 0; ps[j] = 0.f;
        if (i < cnt) {
            const int e = ebufA[a0 + i];
            ev[j] = e;
            ps[j] = p_src[e & 0x1FFFF];
            rk[j] = atomicAdd(&lhist[(e >> 17) & (CWIN - 1)], 1);
        }
    }
    __syncthreads();

    if (t < 64) {
        const int own = lhist[t];
        int val = own;
        #pragma unroll
        for (int s = 1; s < 64; s <<= 1) {
            const int n = __shfl_up(val, s);
            if (t >= s) val += n;
        }
        lbase[t] = val - own;
    }
    __syncthreads();

    #pragma unroll
    for (int j = 0; j < 6; ++j) {
        const int i = t + j * 256;
        if (i < cnt) {
            const int e = ev[j];
            const int ln = (e >> 17) & (CWIN - 1);
            const float ex = __expf(fmaxf(ps[j] + pdl[ln], 0.f));
            ledge[lbase[ln] + rk[j]] = make_int2(e & 0x1FFFF, __float_as_int(ex));
        }
    }
    __syncthreads();

    const int lane = t & 63;
    const int wv = t >> 6;
    const int grp = lane >> 4;
    const int ci = lane & 15;
    const int c4 = ci * 4;

    #pragma unroll
    for (int rr = 0; rr < 4; ++rr) {
        const int ln = wv * 16 + rr * 4 + grp;
        const int node = wbase + ln;
        const int sb = lbase[ln];
        const int d  = (node < N_NODES) ? lhist[ln] : 0;

        float ssum = 0.f;
        float a0f = 0.f, a1f = 0.f, a2f = 0.f, a3f = 0.f;

        #pragma unroll 4
        for (int k = 0; k < d; ++k) {
            const int2 ed = ledge[sb + k];
            const float ex = __int_as_float(ed.y);
            const uint2 wr = *(const uint2*)(Wh + (size_t)ed.x * OUT_DIM + c4);
            ssum += ex;
            a0f = fmaf(ex, __uint_as_float(wr.x << 16), a0f);
            a1f = fmaf(ex, __uint_as_float(wr.x & 0xFFFF0000u), a1f);
            a2f = fmaf(ex, __uint_as_float(wr.y << 16), a2f);
            a3f = fmaf(ex, __uint_as_float(wr.y & 0xFFFF0000u), a3f);
        }

        if (node < N_NODES) {
            const float inv = (d > 0) ? 1.f / ssum : 0.f;
            float* ob = out + (size_t)node * OUT_DIM;
            ob[ci]      = a0f * inv;
            ob[16 + ci] = a1f * inv;
            ob[32 + ci] = a2f * inv;
            ob[48 + ci] = a3f * inv;
        }
    }
}

// ---------------------------------------------------------------------------
extern "C" void kernel_launch(void* const* d_in, const int* in_sizes, int n_in,
                              void* d_out, int out_size, void* d_ws, size_t ws_size,
                              hipStream_t stream)
{
    const float* h  = (const float*)d_in[0];
    const int* src  = (const int*)d_in[1];
    const int* dst  = (const int*)d_in[2];
    const float* W  = (const float*)d_in[3];
    const float* a  = (const float*)d_in[4];
    float* out = (float*)d_out;

    // workspace layout (bytes); every buffer write-before-read
    char* ws = (char*)d_ws;
    unsigned short* WhB = (unsigned short*)(ws);      // 12,800,000 (bf16, permuted)
    float* p_src   = (float*)(ws + 12800000);         //    400,000
    float* p_dst   = (float*)(ws + 13200000);         //    400,000
    int*   cur2dT  = (int*)  (ws + 13600000);         //  1,600,512 (256*1563)
    int*   bsum    = (int*)  (ws + 15200512);         //        392
    int*   ebufA   = (int*)  (ws + 15200904);         //  6,400,000
    unsigned short* WB = (unsigned short*)(ws + 21601024); // 32,768 B, 256-aligned

    gat_hist_wprep<<<NPART + 2, 1024, 0, stream>>>(dst, cur2dT, W, WB);
    gat_scan1<<<SCAN_BLK, 1024, 0, stream>>>(cur2dT, bsum);
    gat_gemm_scatter<<<GEMM_BLKS + NPART, 1024, 0, stream>>>(
        h, WB, a, WhB, p_src, p_dst, src, dst, cur2dT, bsum, ebufA);
    gat_agg_fused<<<NCB, 256, 0, stream>>>(ebufA, cur2dT, bsum, p_src, p_dst,
                                           WhB, out);
}

// Round 23
// 85.288 us; speedup vs baseline: 1.2187x; 1.0535x over previous
//
#include <hip/hip_runtime.h>
#include <hip/hip_bf16.h>
#include <math.h>
#include <stdint.h>

#define N_NODES 100000
#define N_EDGES 1600000
#define IN_DIM 256
#define OUT_DIM 64

#define CWIN  64                          // nodes per window
#define NCB   1563                        // ceil(100000/64)
#define NPART 256                         // 256 * 6250 = 1.6M exact
#define EPP   (N_EDGES / NPART)           // 6250
#define EBCAP 1536                        // fixed window capacity (mean 1024 + 16σ)
#define MAXE  EBCAP

#define GEMM_BLKS ((N_NODES + 255) / 256) // 391 blocks x 256 nodes (16 waves)

// ebufA layout: [window][EBCAP]; gcur[w] = edge count of window w (post-mega).
// Wh stored PERMUTED: Wh'[row][cl*4+nt] = Wh[row][nt*16+cl]

typedef __attribute__((ext_vector_type(8))) short bh8;   // 8 x bf16 frag
typedef __attribute__((ext_vector_type(4))) float f4;    // mfma accumulator

typedef __attribute__((address_space(1))) const void GV;
typedef __attribute__((address_space(3))) void LV;

// f32 -> bf16 round-to-nearest-even
static __device__ __forceinline__ unsigned short f2bf(float f) {
    unsigned u = __float_as_uint(f);
    unsigned r = (u + 0x7FFFu + ((u >> 16) & 1u)) >> 16;
    return (unsigned short)r;
}

// ---------------------------------------------------------------------------
// MEGA kernel: gemm (blocks 0..GEMM_BLKS-1) ∥ scatter (blocks GEMM_BLKS..).
// gemm: R20/R22 body; W staged in-kernel f32->bf16 frag layout (wprep gone).
// scatter: two-level reservation CSR build -- LDS hist over 1563 windows,
// ONE global atomicAdd per (window,block) to reserve a run in the window's
// fixed-capacity region, then LDS-cursor writes. No scan, no hist kernel.
// (Edge order within a window varies run-to-run -> output differs only by
// f32 sum rounding, far below threshold.)
// ---------------------------------------------------------------------------
__global__ __launch_bounds__(1024) void gat_mega(
    const float* __restrict__ h, const float* __restrict__ W,
    const float* __restrict__ a, unsigned short* __restrict__ WhB,
    float* __restrict__ p_src, float* __restrict__ p_dst,
    const int* __restrict__ src, const int* __restrict__ dst,
    int* __restrict__ gcur, int* __restrict__ ebufA)
{
    __shared__ __align__(16) unsigned short Wlds[64 * 256];   // 32 KB

    const int t = threadIdx.x;

    // ---- scatter role ----
    if (blockIdx.x >= GEMM_BLKS) {
        const int part = blockIdx.x - GEMM_BLKS;
        int* lh   = (int*)Wlds;            // [NCB]
        int* lcur = ((int*)Wlds) + NCB;    // [NCB]

        for (int i = t; i < NCB; i += 1024) lh[i] = 0;
        __syncthreads();
        const int e0 = part * EPP;
        for (int e = e0 + t; e < e0 + EPP; e += 1024)
            atomicAdd(&lh[dst[e] >> 6], 1);
        __syncthreads();
        for (int i = t; i < NCB; i += 1024) {
            const int c = lh[i];
            lcur[i] = c ? atomicAdd(&gcur[i], c) : 0;   // reserve run
        }
        __syncthreads();
        for (int e = e0 + t; e < e0 + EPP; e += 1024) {
            const int se = src[e], de = dst[e];
            const int w = de >> 6;
            const int off = atomicAdd(&lcur[w], 1);     // base .. base+c
            ebufA[w * EBCAP + off] = se | ((de & (CWIN - 1)) << 17);
        }
        return;
    }

    // ---- gemm role ----
    const int lane = t & 63;
    const int wv = t >> 6;                 // 0..15
    const int cl = lane & 15;
    const int g  = lane >> 4;
    const int node0 = blockIdx.x * 256 + wv * 16;

    // stage W in-kernel: 2 frag-layout cells per thread (2048 cells total)
    #pragma unroll
    for (int cc = 0; cc < 2; ++cc) {
        const int cell = t + cc * 1024;    // 0..2047
        const int col = cell & 63;
        const int k16 = cell >> 6;         // 0..31
        const float4 lo = *(const float4*)(W + col * IN_DIM + k16 * 8);
        const float4 hi = *(const float4*)(W + col * IN_DIM + k16 * 8 + 4);
        unsigned short tmp[8];
        tmp[0] = f2bf(lo.x); tmp[1] = f2bf(lo.y);
        tmp[2] = f2bf(lo.z); tmp[3] = f2bf(lo.w);
        tmp[4] = f2bf(hi.x); tmp[5] = f2bf(hi.y);
        tmp[6] = f2bf(hi.z); tmp[7] = f2bf(hi.w);
        *(uint4*)&Wlds[cell * 8] = *(uint4*)tmp;
    }
    __syncthreads();

    int row = node0 + cl;
    row = (row < N_NODES) ? row : N_NODES - 1;
    const float* __restrict__ hp = h + (size_t)row * IN_DIM + g * 8;

    f4 acc[4];
    #pragma unroll
    for (int nt = 0; nt < 4; ++nt) acc[nt] = (f4){0.f, 0.f, 0.f, 0.f};

    #pragma unroll
    for (int j = 0; j < 8; ++j) {
        const float4 lo = *(const float4*)(hp + j * 32);
        const float4 hi = *(const float4*)(hp + j * 32 + 4);
        bh8 af;
        af[0] = (short)f2bf(lo.x); af[1] = (short)f2bf(lo.y);
        af[2] = (short)f2bf(lo.z); af[3] = (short)f2bf(lo.w);
        af[4] = (short)f2bf(hi.x); af[5] = (short)f2bf(hi.y);
        af[6] = (short)f2bf(hi.z); af[7] = (short)f2bf(hi.w);

        #pragma unroll
        for (int nt = 0; nt < 4; ++nt) {
            const bh8 bf = *(const bh8*)&Wlds[(((j * 4 + g) * 64) + nt * 16 + cl) * 8];
            acc[nt] = __builtin_amdgcn_mfma_f32_16x16x32_bf16(af, bf, acc[nt], 0, 0, 0);
        }
    }

    float aS[4], aD[4];
    #pragma unroll
    for (int nt = 0; nt < 4; ++nt) {
        aS[nt] = a[nt * 16 + cl];
        aD[nt] = a[OUT_DIM + nt * 16 + cl];
    }

    #pragma unroll
    for (int r = 0; r < 4; ++r) {
        const int orow = node0 + g * 4 + r;
        float ps = 0.f, pd = 0.f;
        #pragma unroll
        for (int nt = 0; nt < 4; ++nt) {
            ps = fmaf(acc[nt][r], aS[nt], ps);
            pd = fmaf(acc[nt][r], aD[nt], pd);
        }
        #pragma unroll
        for (int o = 8; o > 0; o >>= 1) {
            ps += __shfl_xor(ps, o);
            pd += __shfl_xor(pd, o);
        }
        if (orow < N_NODES) {
            const unsigned lo2 = (unsigned)f2bf(acc[0][r]) |
                                 ((unsigned)f2bf(acc[1][r]) << 16);
            const unsigned hi2 = (unsigned)f2bf(acc[2][r]) |
                                 ((unsigned)f2bf(acc[3][r]) << 16);
            *(uint2*)&WhB[(size_t)orow * OUT_DIM + cl * 4] = make_uint2(lo2, hi2);
            if (cl == 0) { p_src[orow] = ps; p_dst[orow] = pd; }
        }
    }
}

// ---------------------------------------------------------------------------
// Fused node-sort + aggregation. Bounds are now trivially [w*EBCAP,
// w*EBCAP + gcnt[w]) -- no scan, no bsum prefix.
// ---------------------------------------------------------------------------
__global__ __launch_bounds__(256) void gat_agg_fused(
    const int* __restrict__ ebufA, const int* __restrict__ gcnt,
    const float* __restrict__ p_src, const float* __restrict__ p_dst,
    const unsigned short* __restrict__ Wh, float* __restrict__ out)
{
    __shared__ int2 ledge[MAXE];          // 12 KB: {sv, ex_bits} binned
    __shared__ int lhist[CWIN], lbase[CWIN];
    __shared__ float pdl[CWIN];

    const int t = threadIdx.x;
    const int cb = blockIdx.x;
    const int a0 = cb * EBCAP;
    const int cnt = min(gcnt[cb], MAXE);
    const int wbase = cb * CWIN;

    if (t < CWIN) {
        lhist[t] = 0;
        const int node = wbase + t;
        pdl[t] = (node < N_NODES) ? p_dst[node] : 0.f;
    }
    __syncthreads();

    int   ev[6], rk[6];
    float ps[6];
    #pragma unroll
    for (int j = 0; j < 6; ++j) {
        const int i = t + j * 256;
        ev[j] = 0; rk[j] = 0; ps[j] = 0.f;
        if (i < cnt) {
            const int e = ebufA[a0 + i];
            ev[j] = e;
            ps[j] = p_src[e & 0x1FFFF];
            rk[j] = atomicAdd(&lhist[(e >> 17) & (CWIN - 1)], 1);
        }
    }
    __syncthreads();

    if (t < 64) {
        const int own = lhist[t];
        int val = own;
        #pragma unroll
        for (int s = 1; s < 64; s <<= 1) {
            const int n = __shfl_up(val, s);
            if (t >= s) val += n;
        }
        lbase[t] = val - own;
    }
    __syncthreads();

    #pragma unroll
    for (int j = 0; j < 6; ++j) {
        const int i = t + j * 256;
        if (i < cnt) {
            const int e = ev[j];
            const int ln = (e >> 17) & (CWIN - 1);
            const float ex = __expf(fmaxf(ps[j] + pdl[ln], 0.f));
            ledge[lbase[ln] + rk[j]] = make_int2(e & 0x1FFFF, __float_as_int(ex));
        }
    }
    __syncthreads();

    const int lane = t & 63;
    const int wv = t >> 6;
    const int grp = lane >> 4;
    const int ci = lane & 15;
    const int c4 = ci * 4;

    #pragma unroll
    for (int rr = 0; rr < 4; ++rr) {
        const int ln = wv * 16 + rr * 4 + grp;
        const int node = wbase + ln;
        const int sb = lbase[ln];
        const int d  = (node < N_NODES) ? lhist[ln] : 0;

        float ssum = 0.f;
        float a0f = 0.f, a1f = 0.f, a2f = 0.f, a3f = 0.f;

        #pragma unroll 4
        for (int k = 0; k < d; ++k) {
            const int2 ed = ledge[sb + k];
            const float ex = __int_as_float(ed.y);
            const uint2 wr = *(const uint2*)(Wh + (size_t)ed.x * OUT_DIM + c4);
            ssum += ex;
            a0f = fmaf(ex, __uint_as_float(wr.x << 16), a0f);
            a1f = fmaf(ex, __uint_as_float(wr.x & 0xFFFF0000u), a1f);
            a2f = fmaf(ex, __uint_as_float(wr.y << 16), a2f);
            a3f = fmaf(ex, __uint_as_float(wr.y & 0xFFFF0000u), a3f);
        }

        if (node < N_NODES) {
            const float inv = (d > 0) ? 1.f / ssum : 0.f;
            float* ob = out + (size_t)node * OUT_DIM;
            ob[ci]      = a0f * inv;
            ob[16 + ci] = a1f * inv;
            ob[32 + ci] = a2f * inv;
            ob[48 + ci] = a3f * inv;
        }
    }
}

// ---------------------------------------------------------------------------
extern "C" void kernel_launch(void* const* d_in, const int* in_sizes, int n_in,
                              void* d_out, int out_size, void* d_ws, size_t ws_size,
                              hipStream_t stream)
{
    const float* h  = (const float*)d_in[0];
    const int* src  = (const int*)d_in[1];
    const int* dst  = (const int*)d_in[2];
    const float* W  = (const float*)d_in[3];
    const float* a  = (const float*)d_in[4];
    float* out = (float*)d_out;

    // workspace layout (bytes), total ~23.2 MB; every buffer write-before-read
    char* ws = (char*)d_ws;
    unsigned short* WhB = (unsigned short*)(ws);      // 12,800,000 (bf16, permuted)
    float* p_src   = (float*)(ws + 12800000);         //    400,000
    float* p_dst   = (float*)(ws + 13200000);         //    400,000
    int*   gcur    = (int*)  (ws + 13600000);         //      6,252
    int*   ebufA   = (int*)  (ws + 13606252 + 4);     //  9,603,072 (NCB*EBCAP*4)

    hipMemsetAsync(gcur, 0, NCB * sizeof(int), stream);
    gat_mega<<<GEMM_BLKS + NPART, 1024, 0, stream>>>(
        h, W, a, WhB, p_src, p_dst, src, dst, gcur, ebufA);
    gat_agg_fused<<<NCB, 256, 0, stream>>>(ebufA, gcur, p_src, p_dst, WhB, out);
}